// Round 11
// baseline (284.441 us; speedup 1.0000x reference)
//
#include <hip/hip_runtime.h>
#include <math.h>

#define BDIM 2
#define TT 1024
#define NH 8
#define HD 64
#define NTOPK 16
#define NBH 16     // BDIM*NH
#define NTOK 16384 // NBH*TT

// ---------------------------------------------------------------------------
// Collapse the linear-linear pair MLPs into 128-dim fp64 vectors.
// ---------------------------------------------------------------------------
__global__ __launch_bounds__(256) void k_collapse64(
    const float* __restrict__ Wpi, const float* __restrict__ bpi,
    const float* __restrict__ Wpo, const float* __restrict__ bpo,
    const float* __restrict__ Wti, const float* __restrict__ bti,
    const float* __restrict__ Wto, const float* __restrict__ bto,
    double* __restrict__ wphid, double* __restrict__ wtaud,
    double* __restrict__ ccd) {
  int tid = threadIdx.x;
  int blk = blockIdx.x;
  if (blk < 16) {
    int r = blk * 16 + (tid >> 4);
    int l = tid & 15;
    double s = 0.;
    if (r < 128) {
      for (int i = 0; i < 32; ++i)
        s += (double)Wpi[r * 512 + l + 16 * i] * (double)Wpo[l + 16 * i];
    } else {
      int rr = r - 128;
      for (int i = 0; i < 16; ++i)
        s += (double)Wti[rr * 256 + l + 16 * i] * (double)Wto[l + 16 * i];
    }
#pragma unroll
    for (int off = 8; off >= 1; off >>= 1) s += __shfl_xor(s, off, 64);
    if (l == 0) {
      if (r < 128) wphid[r] = s;
      else wtaud[r - 128] = s;
    }
  } else {
    int lane = tid & 63;
    if (tid < 64) {
      double p = 0.;
      for (int c = lane; c < 512; c += 64) p += (double)bpi[c] * (double)Wpo[c];
#pragma unroll
      for (int off = 32; off >= 1; off >>= 1) p += __shfl_xor(p, off, 64);
      if (lane == 0) ccd[0] = p + (double)bpo[0];
    } else if (tid < 128) {
      double p = 0.;
      for (int c = lane; c < 256; c += 64) p += (double)bti[c] * (double)Wto[c];
#pragma unroll
      for (int off = 32; off >= 1; off >>= 1) p += __shfl_xor(p, off, 64);
      if (lane == 0) ccd[1] = p + (double)bto[0];
    }
  }
}

// ---------------------------------------------------------------------------
// fp32 GEMM, strict sequential-k fp32 FMA per output element (BLAS-order).
// R1 structure + R9 XOR-swizzled As stores (conflicts 2.36M->0.79M, 54->50us).
// CLOSED: R2 wave-uniform A (3.7x regress), R3 dbuf (neutral), R7 BM=32
// (issue/ILP-bound, not occupancy). Micro-tile >= 4x4 is load-bearing.
// ---------------------------------------------------------------------------
__device__ __forceinline__ void gemm_body(
    const float* __restrict__ A, const float* __restrict__ W,
    const float* __restrict__ bias, float* __restrict__ out,
    int bm, int bn, int mode) {
  __shared__ float As[32][68];
  __shared__ float Bs[32][64];
  const int tid = threadIdx.x;
  const int tx = tid & 15;
  const int ty = tid >> 4;
  float acc[4][4] = {{0.f, 0.f, 0.f, 0.f}};
  for (int k0 = 0; k0 < 512; k0 += 32) {
#pragma unroll
    for (int i = 0; i < 2; ++i) {
      int idx = i * 256 + tid;     // 0..511
      int row = idx >> 3;          // 0..63
      int c4 = (idx & 7) << 2;     // 0..28
      int sw = (idx & 7) << 3;     // swizzle bits 3-5
      int rs = row ^ sw;           // 0..63
      float4 av = *(const float4*)&A[(bm + row) * 512 + k0 + c4];
      As[c4 + 0][rs] = av.x;
      As[c4 + 1][rs] = av.y;
      As[c4 + 2][rs] = av.z;
      As[c4 + 3][rs] = av.w;
    }
#pragma unroll
    for (int i = 0; i < 2; ++i) {
      int idx = i * 256 + tid;     // 0..511
      int br = idx >> 4;           // 0..31
      int bc = (idx & 15) << 2;
      *(float4*)&Bs[br][bc] = *(const float4*)&W[(k0 + br) * 512 + bn + bc];
    }
    __syncthreads();
#pragma unroll
    for (int kk = 0; kk < 32; ++kk) {
      const int sr = ((kk >> 2) & 7) << 3;
      float4 a = *(const float4*)&As[kk][(ty * 4) ^ sr];
      float4 b = *(const float4*)&Bs[kk][tx << 2];
      acc[0][0] = fmaf(a.x, b.x, acc[0][0]);
      acc[0][1] = fmaf(a.x, b.y, acc[0][1]);
      acc[0][2] = fmaf(a.x, b.z, acc[0][2]);
      acc[0][3] = fmaf(a.x, b.w, acc[0][3]);
      acc[1][0] = fmaf(a.y, b.x, acc[1][0]);
      acc[1][1] = fmaf(a.y, b.y, acc[1][1]);
      acc[1][2] = fmaf(a.y, b.z, acc[1][2]);
      acc[1][3] = fmaf(a.y, b.w, acc[1][3]);
      acc[2][0] = fmaf(a.z, b.x, acc[2][0]);
      acc[2][1] = fmaf(a.z, b.y, acc[2][1]);
      acc[2][2] = fmaf(a.z, b.z, acc[2][2]);
      acc[2][3] = fmaf(a.z, b.w, acc[2][3]);
      acc[3][0] = fmaf(a.w, b.x, acc[3][0]);
      acc[3][1] = fmaf(a.w, b.y, acc[3][1]);
      acc[3][2] = fmaf(a.w, b.z, acc[3][2]);
      acc[3][3] = fmaf(a.w, b.w, acc[3][3]);
    }
    __syncthreads();
  }
#pragma unroll
  for (int i = 0; i < 4; ++i) {
    int row = bm + ty * 4 + i;
    float4 r;
    r.x = acc[i][0] + bias[bn + tx * 4 + 0];
    r.y = acc[i][1] + bias[bn + tx * 4 + 1];
    r.z = acc[i][2] + bias[bn + tx * 4 + 2];
    r.w = acc[i][3] + bias[bn + tx * 4 + 3];
    if (mode == 0) {
      *(float4*)&out[row * 512 + bn + tx * 4] = r;
    } else {
      int bb = row >> 10;
      int tt2 = row & 1023;
      int head = bn >> 6;
      *(float4*)&out[(((bb * NH + head) * TT + tt2) << 6) + tx * 4] = r;
    }
  }
}

__global__ __launch_bounds__(256) void k_gemm(
    const float* __restrict__ A, const float* __restrict__ W,
    const float* __restrict__ bias, float* __restrict__ out, int mode) {
  gemm_body(A, W, bias, out, blockIdx.y * 64, blockIdx.x * 64, mode);
}

__global__ __launch_bounds__(256) void k_gemm_qkv(
    const float* __restrict__ A,
    const float* __restrict__ Wq, const float* __restrict__ bq,
    const float* __restrict__ Wk, const float* __restrict__ bk,
    const float* __restrict__ Wv, const float* __restrict__ bv,
    float* __restrict__ Qf, float* __restrict__ Kf, float* __restrict__ Vf) {
  int which = blockIdx.x >> 3;
  int bn = (blockIdx.x & 7) * 64;
  const float* W = (which == 0) ? Wq : (which == 1) ? Wk : Wv;
  const float* b = (which == 0) ? bq : (which == 1) ? bk : bv;
  float* out = (which == 0) ? Qf : (which == 1) ? Kf : Vf;
  gemm_body(A, W, b, out, blockIdx.y * 64, bn, 1);
}

// ---------------------------------------------------------------------------
// Per-token scalars in fp64 — v2 (R8, coalesced LDS staging).
// ---------------------------------------------------------------------------
__global__ __launch_bounds__(256) void k_tokscal64(
    const float* __restrict__ Qg, const float* __restrict__ Kg,
    const double* __restrict__ wphid, const float* __restrict__ Wta,
    const float* __restrict__ Wtb, const double* __restrict__ wtaud,
    double4* __restrict__ sqd4, double4* __restrict__ skd4) {
  __shared__ double wp[128], wa[128], wb[128], wt[128];
  __shared__ float Qs[128][64];
  __shared__ float Ks[128][64];
  const int tid = threadIdx.x;
  if (tid < 128) {
    wp[tid] = wphid[tid];
    wa[tid] = (double)Wta[tid];
    wb[tid] = (double)Wtb[tid];
    wt[tid] = wtaud[tid];
  }
  const int tok0 = blockIdx.x * 128;
#pragma unroll
  for (int i = 0; i < 8; ++i) {
    int idx = i * 256 + tid;          // 0..2047
    int row = idx >> 4;               // 0..127
    int c4 = (idx & 15) << 2;         // 0..60
    *(float4*)&Qs[row][c4] = *(const float4*)&Qg[(size_t)(tok0 + row) * 64 + c4];
    *(float4*)&Ks[row][c4] = *(const float4*)&Kg[(size_t)(tok0 + row) * 64 + c4];
  }
  __syncthreads();
  const int r = tid >> 1;        // token row 0..127
  const int h = tid & 1;         // half: d in [h*32, h*32+32)
  const int dbase = h << 5;
  double sp = 0., sa = 0., sb = 0., st = 0.;
  double kp = 0., ka = 0., kb2 = 0., kt = 0.;
#pragma unroll
  for (int i = 0; i < 32; ++i) {
    int d = dbase + ((i + r) & 31);   // rotated -> conflict-free banks
    double q = (double)Qs[r][d];
    double k = (double)Ks[r][d];
    sp += q * wp[d];
    sa += q * wa[d];
    sb += q * wb[d];
    st += q * wt[d];
    kp += k * wp[64 + d];
    ka += k * wa[64 + d];
    kb2 += k * wb[64 + d];
    kt += k * wt[64 + d];
  }
  sp += __shfl_xor(sp, 1, 64);  sa += __shfl_xor(sa, 1, 64);
  sb += __shfl_xor(sb, 1, 64);  st += __shfl_xor(st, 1, 64);
  kp += __shfl_xor(kp, 1, 64);  ka += __shfl_xor(ka, 1, 64);
  kb2 += __shfl_xor(kb2, 1, 64); kt += __shfl_xor(kt, 1, 64);
  const int tok = tok0 + r;
  if (h == 0) sqd4[tok] = make_double4(sp, sa, sb, st);
  else        skd4[tok] = make_double4(kp, ka, kb2, kt);
}

// ---------------------------------------------------------------------------
// FUSED attention v4 — registers scores, SPILL-FREE.
// R10's f3 spilled (v[8][16]=128 floats; VGPR_Count=100 proved scratch) ->
// 115us scratch-latency-bound. f4 halves per-thread score state:
// 16 q-rows/block, 4 rows/wave, v[4][16]=64 floats. LDS 70.5KB -> still
// 2 blocks/CU (LDS-bound; VGPR non-binding). K staged 2x more total
// (256MB from L2 ~ 7us, cheap).
//  * Lane l holds v[r][t*4+j] = score col t*256+l*4+j — k_topk's layout;
//    R1-proven selection + fp32 finish run verbatim per row.
//  * Scores: d strictly ascending, one fmaf per d per element ->
//    bit-identical to k_score. Selection set unchanged.
// Grid (64, 16) = 1024 blocks, 256 threads.
// ---------------------------------------------------------------------------
__global__ __launch_bounds__(256) void k_attn_f4(
    const float* __restrict__ Qg, const float* __restrict__ Kg,
    const float* __restrict__ Vg, const double4* __restrict__ sqd4,
    const double4* __restrict__ skd4, const double* __restrict__ ccd,
    const float* __restrict__ btaP, const float* __restrict__ btbP,
    float* __restrict__ C) {
  __shared__ float qs[16][64];
  __shared__ float KT[64][260];   // [d][kr^sw], transposed swizzled K tile
  const int bh = blockIdx.y;
  const int q0 = blockIdx.x * 16;
  const int tid = threadIdx.x;
  const int lane = tid & 63;
  const int wv = tid >> 6;

  // stage Q: 16 rows x 64 d, coalesced (one float4 per thread)
  {
    int row = tid >> 4;             // 0..15
    int c4 = (tid & 15) << 2;       // 0..60
    *(float4*)&qs[row][c4] =
        *(const float4*)&Qg[(size_t)(bh * TT + q0 + row) * 64 + c4];
  }

  float v[4][16];
#pragma unroll
  for (int r = 0; r < 4; ++r)
#pragma unroll
    for (int s = 0; s < 16; ++s) v[r][s] = 0.f;

#pragma unroll
  for (int t = 0; t < 4; ++t) {
    __syncthreads();   // protect KT (and qs on t=0) before overwrite
    // stage K tile t: 256 rows x 64 d, coalesced (16 float4 per thread)
#pragma unroll
    for (int i = 0; i < 16; ++i) {
      int idx = i * 256 + tid;      // 0..4095
      int kr = idx >> 4;            // 0..255
      int d4 = (idx & 15) << 2;     // 0..60
      float4 kv =
          *(const float4*)&Kg[(size_t)(bh * TT + t * 256 + kr) * 64 + d4];
      int krs = kr ^ (((d4 >> 2) & 7) << 3);
      KT[d4 + 0][krs] = kv.x;
      KT[d4 + 1][krs] = kv.y;
      KT[d4 + 2][krs] = kv.z;
      KT[d4 + 3][krs] = kv.w;
    }
    __syncthreads();
    // compute: 16 d4-blocks; 4 K b128 reads serve 4 rows x 16 FMA
#pragma unroll 1
    for (int d4 = 0; d4 < 64; d4 += 4) {
      const int cbase = (lane << 2) ^ (((d4 >> 2) & 7) << 3);
      float4 k0 = *(const float4*)&KT[d4 + 0][cbase];
      float4 k1 = *(const float4*)&KT[d4 + 1][cbase];
      float4 k2 = *(const float4*)&KT[d4 + 2][cbase];
      float4 k3 = *(const float4*)&KT[d4 + 3][cbase];
#pragma unroll
      for (int r = 0; r < 4; ++r) {
        float4 q4 = *(const float4*)&qs[wv * 4 + r][d4];
        // per accumulator: d4+0 -> d4+1 -> d4+2 -> d4+3 (d ascending)
        v[r][t * 4 + 0] = fmaf(q4.x, k0.x, v[r][t * 4 + 0]);
        v[r][t * 4 + 1] = fmaf(q4.x, k0.y, v[r][t * 4 + 1]);
        v[r][t * 4 + 2] = fmaf(q4.x, k0.z, v[r][t * 4 + 2]);
        v[r][t * 4 + 3] = fmaf(q4.x, k0.w, v[r][t * 4 + 3]);
        v[r][t * 4 + 0] = fmaf(q4.y, k1.x, v[r][t * 4 + 0]);
        v[r][t * 4 + 1] = fmaf(q4.y, k1.y, v[r][t * 4 + 1]);
        v[r][t * 4 + 2] = fmaf(q4.y, k1.z, v[r][t * 4 + 2]);
        v[r][t * 4 + 3] = fmaf(q4.y, k1.w, v[r][t * 4 + 3]);
        v[r][t * 4 + 0] = fmaf(q4.z, k2.x, v[r][t * 4 + 0]);
        v[r][t * 4 + 1] = fmaf(q4.z, k2.y, v[r][t * 4 + 1]);
        v[r][t * 4 + 2] = fmaf(q4.z, k2.z, v[r][t * 4 + 2]);
        v[r][t * 4 + 3] = fmaf(q4.z, k2.w, v[r][t * 4 + 3]);
        v[r][t * 4 + 0] = fmaf(q4.w, k3.x, v[r][t * 4 + 0]);
        v[r][t * 4 + 1] = fmaf(q4.w, k3.y, v[r][t * 4 + 1]);
        v[r][t * 4 + 2] = fmaf(q4.w, k3.z, v[r][t * 4 + 2]);
        v[r][t * 4 + 3] = fmaf(q4.w, k3.w, v[r][t * 4 + 3]);
      }
    }
  }

  // ---- selection + fp32 finish, verbatim R1-proven logic, per row ----
  const double cphi = ccd[0];
  const double ctau = ccd[1];
  const double bta0 = (double)btaP[0];
  const double btb0 = (double)btbP[0];
  const int bb = bh >> 3;
  const int hh = bh & 7;
  const float* Vbh = Vg + (size_t)bh * (TT * 64);
  const int lbase = lane << 2;
#pragma unroll
  for (int r = 0; r < 4; ++r) {
    const int qa = q0 + wv * 4 + r;
    float gv[4];
    int gi[4];
#pragma unroll
    for (int g = 0; g < 4; ++g) {
      float nv = v[r][4 * g];
      int ne = 0;
#pragma unroll
      for (int e = 1; e < 4; ++e) {
        if (v[r][4 * g + e] > nv) { nv = v[r][4 * g + e]; ne = e; }
      }
      gv[g] = nv;
      gi[g] = (g << 8) | lbase | ne;
    }
    int myk = 0;
#pragma unroll 1
    for (int it = 0; it < NTOPK; ++it) {
      float cv = gv[0];
      int ci = gi[0];
#pragma unroll
      for (int g = 1; g < 4; ++g) {
        if (gv[g] > cv) { cv = gv[g]; ci = gi[g]; }
      }
      float M = cv;
#pragma unroll
      for (int off = 32; off >= 1; off >>= 1)
        M = fmaxf(M, __shfl_xor(M, off, 64));
      unsigned long long tied = __ballot(cv == M);
      int J;
      if (__popcll(tied) == 1) {
        int src = __ffsll(tied) - 1;
        J = __builtin_amdgcn_readfirstlane(__shfl(ci, src, 64));
      } else {
        int cj = (cv == M) ? ci : 0x7FFFFFFF;
#pragma unroll
        for (int off = 32; off >= 1; off >>= 1) {
          int oj = __shfl_xor(cj, off, 64);
          cj = (oj < cj) ? oj : cj;
        }
        J = __builtin_amdgcn_readfirstlane(cj);
      }
      if (lane == it) myk = J;
      const int owner = (J >> 2) & 63;
      const int g2 = J >> 8;
      const int e2 = J & 3;
      const bool isown = (lane == owner);
#pragma unroll
      for (int g = 0; g < 4; ++g) {
        if (g == g2) {  // uniform branch
#pragma unroll
          for (int e = 0; e < 4; ++e) {
            if (e == e2) v[r][4 * g + e] = isown ? -INFINITY : v[r][4 * g + e];
          }
          float nv = v[r][4 * g];
          int ne = 0;
#pragma unroll
          for (int e = 1; e < 4; ++e) {
            if (v[r][4 * g + e] > nv) { nv = v[r][4 * g + e]; ne = e; }
          }
          gv[g] = nv;
          gi[g] = (g << 8) | lbase | ne;
        }
      }
    }
    // fp32 finish (identical to k_topk's proven path)
    double4 sq = sqd4[(size_t)bh * TT + qa];
    float logit = -INFINITY;
    if (lane < 16) {
      double4 sk = skd4[bh * TT + myk];
      float xs = (float)(sq.x + sk.x + cphi);
      float ta = (float)(sq.y + sk.y + bta0);
      float tb = (float)(sq.z + sk.z + btb0);
      float tl = (float)(sq.w + sk.w + ctau);
      float phi = 1.f / (1.f + __expf(-xs));
      float ti = 1.f / (1.f + __expf(-(ta + tb)));          // T_SCALAR = 1
      float tau = fmaxf(tl, 0.f) + log1pf(__expf(-fabsf(tl))) + 1e-6f;
      logit = phi / tau * (1.f - __expf(-tau * ti));
    }
    float m = logit;
#pragma unroll
    for (int off = 8; off >= 1; off >>= 1) m = fmaxf(m, __shfl_xor(m, off, 64));
    float e = (lane < 16) ? __expf(logit - m) : 0.f;
    float ssum = e;
#pragma unroll
    for (int off = 8; off >= 1; off >>= 1) ssum += __shfl_xor(ssum, off, 64);
    float w = e / ssum;
    float outv = 0.f;
#pragma unroll
    for (int k2 = 0; k2 < NTOPK; ++k2) {
      float wk = __shfl(w, k2, 64);
      int ik = __shfl(myk, k2, 64);
      outv = fmaf(wk, Vbh[(size_t)ik * 64 + lane], outv);
    }
    C[(bb * TT + qa) * 512 + hh * 64 + lane] = outv;
  }
}

// ---------------------------------------------------------------------------
extern "C" void kernel_launch(void* const* d_in, const int* in_sizes, int n_in,
                              void* d_out, int out_size, void* d_ws, size_t ws_size,
                              hipStream_t stream) {
  (void)in_sizes; (void)n_in; (void)out_size; (void)ws_size;
  const float* x   = (const float*)d_in[0];
  const float* Wq  = (const float*)d_in[1];
  const float* bq  = (const float*)d_in[2];
  const float* Wk  = (const float*)d_in[3];
  const float* bk  = (const float*)d_in[4];
  const float* Wv  = (const float*)d_in[5];
  const float* bv  = (const float*)d_in[6];
  const float* Wo  = (const float*)d_in[7];
  const float* bo  = (const float*)d_in[8];
  const float* Wpi = (const float*)d_in[9];
  const float* bpi = (const float*)d_in[10];
  const float* Wpo = (const float*)d_in[11];
  const float* bpo = (const float*)d_in[12];
  const float* Wta = (const float*)d_in[13];
  const float* bta = (const float*)d_in[14];
  const float* Wtb = (const float*)d_in[15];
  const float* btb = (const float*)d_in[16];
  const float* Wti = (const float*)d_in[17];
  const float* bti = (const float*)d_in[18];
  const float* Wto = (const float*)d_in[19];
  const float* bto = (const float*)d_in[20];

  double* wsd = (double*)d_ws;
  double4* sqd4 = (double4*)wsd;             // 65536 doubles
  double4* skd4 = (double4*)(wsd + 65536);   // 65536 doubles
  double* wphid = wsd + 131072;              // 128
  double* wtaud = wsd + 131200;              // 128
  double* ccd   = wsd + 131328;              // 2 (pad to 131332)
  float* fs = (float*)(wsd + 131332);
  float* Qf = fs;                  // 1,048,576 floats
  float* Kf = fs + 1048576;
  float* Vf = fs + 2097152;
  float* Cf = fs + 3145728;

  hipLaunchKernelGGL(k_collapse64, dim3(17), dim3(256), 0, stream,
                     Wpi, bpi, Wpo, bpo, Wti, bti, Wto, bto, wphid, wtaud, ccd);
  hipLaunchKernelGGL(k_gemm_qkv, dim3(24, 32), dim3(256), 0, stream,
                     x, Wq, bq, Wk, bk, Wv, bv, Qf, Kf, Vf);
  hipLaunchKernelGGL(k_tokscal64, dim3(NTOK / 128), dim3(256), 0, stream,
                     Qf, Kf, wphid, Wta, Wtb, wtaud, sqd4, skd4);
  hipLaunchKernelGGL(k_attn_f4, dim3(64, NBH), dim3(256), 0, stream,
                     Qf, Kf, Vf, sqd4, skd4, ccd, bta, btb, Cf);
  hipLaunchKernelGGL(k_gemm, dim3(8, 32), dim3(256), 0, stream,
                     Cf, Wo, bo, (float*)d_out, 0);
}

// Round 12
// 256.482 us; speedup vs baseline: 1.1090x; 1.1090x over previous
//
#include <hip/hip_runtime.h>
#include <math.h>

#define BDIM 2
#define TT 1024
#define NH 8
#define HD 64
#define NTOPK 16
#define NBH 16     // BDIM*NH
#define NTOK 16384 // NBH*TT

// ---------------------------------------------------------------------------
// Collapse the linear-linear pair MLPs into 128-dim fp64 vectors.
// ---------------------------------------------------------------------------
__global__ __launch_bounds__(256) void k_collapse64(
    const float* __restrict__ Wpi, const float* __restrict__ bpi,
    const float* __restrict__ Wpo, const float* __restrict__ bpo,
    const float* __restrict__ Wti, const float* __restrict__ bti,
    const float* __restrict__ Wto, const float* __restrict__ bto,
    double* __restrict__ wphid, double* __restrict__ wtaud,
    double* __restrict__ ccd) {
  int tid = threadIdx.x;
  int blk = blockIdx.x;
  if (blk < 16) {
    int r = blk * 16 + (tid >> 4);
    int l = tid & 15;
    double s = 0.;
    if (r < 128) {
      for (int i = 0; i < 32; ++i)
        s += (double)Wpi[r * 512 + l + 16 * i] * (double)Wpo[l + 16 * i];
    } else {
      int rr = r - 128;
      for (int i = 0; i < 16; ++i)
        s += (double)Wti[rr * 256 + l + 16 * i] * (double)Wto[l + 16 * i];
    }
#pragma unroll
    for (int off = 8; off >= 1; off >>= 1) s += __shfl_xor(s, off, 64);
    if (l == 0) {
      if (r < 128) wphid[r] = s;
      else wtaud[r - 128] = s;
    }
  } else {
    int lane = tid & 63;
    if (tid < 64) {
      double p = 0.;
      for (int c = lane; c < 512; c += 64) p += (double)bpi[c] * (double)Wpo[c];
#pragma unroll
      for (int off = 32; off >= 1; off >>= 1) p += __shfl_xor(p, off, 64);
      if (lane == 0) ccd[0] = p + (double)bpo[0];
    } else if (tid < 128) {
      double p = 0.;
      for (int c = lane; c < 256; c += 64) p += (double)bti[c] * (double)Wto[c];
#pragma unroll
      for (int off = 32; off >= 1; off >>= 1) p += __shfl_xor(p, off, 64);
      if (lane == 0) ccd[1] = p + (double)bto[0];
    }
  }
}

// ---------------------------------------------------------------------------
// fp32 GEMM, strict sequential-k fp32 FMA per output element (BLAS-order).
// R1 structure + R9 As XOR-swizzle (2.36M->786K conflicts, 54->50.3us)
// + R12 Bs XOR-swizzle (the residual 786K: Bs float4 stores were 8-way —
// bank_quad = bc4 mod 8, br stride 64 == 0 mod 32; store at
// bc ^ ((br&7)<<2) -> exact 2-way (free); read swizzles by (kk&7),
// wave-uniform per kk -> read pattern unchanged). Pure layout permutation,
// bit-identical values and FMA order.
// CLOSED: R2 wave-uniform A (3.7x regress), R3 dbuf (neutral), R7 BM=32
// (issue/ILP-bound, not occupancy). Micro-tile >= 4x4 is load-bearing.
// FUSION ARC CLOSED (R5/R6/R10/R11): all score+topk fusions 115-284us vs
// split ~85us — uncoalesced K (R5), LDS->1 blk/CU (R6), reg spill (R10),
// staging bank conflicts + occupancy (R11). Do not reopen.
// ---------------------------------------------------------------------------
__device__ __forceinline__ void gemm_body(
    const float* __restrict__ A, const float* __restrict__ W,
    const float* __restrict__ bias, float* __restrict__ out,
    int bm, int bn, int mode) {
  __shared__ float As[32][68];
  __shared__ float Bs[32][64];
  const int tid = threadIdx.x;
  const int tx = tid & 15;
  const int ty = tid >> 4;
  float acc[4][4] = {{0.f, 0.f, 0.f, 0.f}};
  for (int k0 = 0; k0 < 512; k0 += 32) {
#pragma unroll
    for (int i = 0; i < 2; ++i) {
      int idx = i * 256 + tid;     // 0..511
      int row = idx >> 3;          // 0..63
      int c4 = (idx & 7) << 2;     // 0..28
      int sw = (idx & 7) << 3;     // swizzle bits 3-5
      int rs = row ^ sw;           // 0..63
      float4 av = *(const float4*)&A[(bm + row) * 512 + k0 + c4];
      As[c4 + 0][rs] = av.x;
      As[c4 + 1][rs] = av.y;
      As[c4 + 2][rs] = av.z;
      As[c4 + 3][rs] = av.w;
    }
#pragma unroll
    for (int i = 0; i < 2; ++i) {
      int idx = i * 256 + tid;     // 0..511
      int br = idx >> 4;           // 0..31
      int bc = (idx & 15) << 2;
      int bcs = bc ^ ((br & 7) << 2);   // R12: break 8-way store conflict
      *(float4*)&Bs[br][bcs] = *(const float4*)&W[(k0 + br) * 512 + bn + bc];
    }
    __syncthreads();
#pragma unroll
    for (int kk = 0; kk < 32; ++kk) {
      const int sr = ((kk >> 2) & 7) << 3;
      float4 a = *(const float4*)&As[kk][(ty * 4) ^ sr];
      float4 b = *(const float4*)&Bs[kk][(tx << 2) ^ ((kk & 7) << 2)];
      acc[0][0] = fmaf(a.x, b.x, acc[0][0]);
      acc[0][1] = fmaf(a.x, b.y, acc[0][1]);
      acc[0][2] = fmaf(a.x, b.z, acc[0][2]);
      acc[0][3] = fmaf(a.x, b.w, acc[0][3]);
      acc[1][0] = fmaf(a.y, b.x, acc[1][0]);
      acc[1][1] = fmaf(a.y, b.y, acc[1][1]);
      acc[1][2] = fmaf(a.y, b.z, acc[1][2]);
      acc[1][3] = fmaf(a.y, b.w, acc[1][3]);
      acc[2][0] = fmaf(a.z, b.x, acc[2][0]);
      acc[2][1] = fmaf(a.z, b.y, acc[2][1]);
      acc[2][2] = fmaf(a.z, b.z, acc[2][2]);
      acc[2][3] = fmaf(a.z, b.w, acc[2][3]);
      acc[3][0] = fmaf(a.w, b.x, acc[3][0]);
      acc[3][1] = fmaf(a.w, b.y, acc[3][1]);
      acc[3][2] = fmaf(a.w, b.z, acc[3][2]);
      acc[3][3] = fmaf(a.w, b.w, acc[3][3]);
    }
    __syncthreads();
  }
#pragma unroll
  for (int i = 0; i < 4; ++i) {
    int row = bm + ty * 4 + i;
    float4 r;
    r.x = acc[i][0] + bias[bn + tx * 4 + 0];
    r.y = acc[i][1] + bias[bn + tx * 4 + 1];
    r.z = acc[i][2] + bias[bn + tx * 4 + 2];
    r.w = acc[i][3] + bias[bn + tx * 4 + 3];
    if (mode == 0) {
      *(float4*)&out[row * 512 + bn + tx * 4] = r;
    } else {
      int bb = row >> 10;
      int tt2 = row & 1023;
      int head = bn >> 6;
      *(float4*)&out[(((bb * NH + head) * TT + tt2) << 6) + tx * 4] = r;
    }
  }
}

__global__ __launch_bounds__(256) void k_gemm(
    const float* __restrict__ A, const float* __restrict__ W,
    const float* __restrict__ bias, float* __restrict__ out, int mode) {
  gemm_body(A, W, bias, out, blockIdx.y * 64, blockIdx.x * 64, mode);
}

__global__ __launch_bounds__(256) void k_gemm_qkv(
    const float* __restrict__ A,
    const float* __restrict__ Wq, const float* __restrict__ bq,
    const float* __restrict__ Wk, const float* __restrict__ bk,
    const float* __restrict__ Wv, const float* __restrict__ bv,
    float* __restrict__ Qf, float* __restrict__ Kf, float* __restrict__ Vf) {
  int which = blockIdx.x >> 3;
  int bn = (blockIdx.x & 7) * 64;
  const float* W = (which == 0) ? Wq : (which == 1) ? Wk : Wv;
  const float* b = (which == 0) ? bq : (which == 1) ? bk : bv;
  float* out = (which == 0) ? Qf : (which == 1) ? Kf : Vf;
  gemm_body(A, W, b, out, blockIdx.y * 64, bn, 1);
}

// ---------------------------------------------------------------------------
// Per-token scalars in fp64 — v2 (R8, coalesced LDS staging).
// ---------------------------------------------------------------------------
__global__ __launch_bounds__(256) void k_tokscal64(
    const float* __restrict__ Qg, const float* __restrict__ Kg,
    const double* __restrict__ wphid, const float* __restrict__ Wta,
    const float* __restrict__ Wtb, const double* __restrict__ wtaud,
    double4* __restrict__ sqd4, double4* __restrict__ skd4) {
  __shared__ double wp[128], wa[128], wb[128], wt[128];
  __shared__ float Qs[128][64];
  __shared__ float Ks[128][64];
  const int tid = threadIdx.x;
  if (tid < 128) {
    wp[tid] = wphid[tid];
    wa[tid] = (double)Wta[tid];
    wb[tid] = (double)Wtb[tid];
    wt[tid] = wtaud[tid];
  }
  const int tok0 = blockIdx.x * 128;
#pragma unroll
  for (int i = 0; i < 8; ++i) {
    int idx = i * 256 + tid;          // 0..2047
    int row = idx >> 4;               // 0..127
    int c4 = (idx & 15) << 2;         // 0..60
    *(float4*)&Qs[row][c4] = *(const float4*)&Qg[(size_t)(tok0 + row) * 64 + c4];
    *(float4*)&Ks[row][c4] = *(const float4*)&Kg[(size_t)(tok0 + row) * 64 + c4];
  }
  __syncthreads();
  const int r = tid >> 1;        // token row 0..127
  const int h = tid & 1;         // half: d in [h*32, h*32+32)
  const int dbase = h << 5;
  double sp = 0., sa = 0., sb = 0., st = 0.;
  double kp = 0., ka = 0., kb2 = 0., kt = 0.;
#pragma unroll
  for (int i = 0; i < 32; ++i) {
    int d = dbase + ((i + r) & 31);   // rotated -> conflict-free banks
    double q = (double)Qs[r][d];
    double k = (double)Ks[r][d];
    sp += q * wp[d];
    sa += q * wa[d];
    sb += q * wb[d];
    st += q * wt[d];
    kp += k * wp[64 + d];
    ka += k * wa[64 + d];
    kb2 += k * wb[64 + d];
    kt += k * wt[64 + d];
  }
  sp += __shfl_xor(sp, 1, 64);  sa += __shfl_xor(sa, 1, 64);
  sb += __shfl_xor(sb, 1, 64);  st += __shfl_xor(st, 1, 64);
  kp += __shfl_xor(kp, 1, 64);  ka += __shfl_xor(ka, 1, 64);
  kb2 += __shfl_xor(kb2, 1, 64); kt += __shfl_xor(kt, 1, 64);
  const int tok = tok0 + r;
  if (h == 0) sqd4[tok] = make_double4(sp, sa, sb, st);
  else        skd4[tok] = make_double4(kp, ka, kb2, kt);
}

// ---------------------------------------------------------------------------
// Score GEMM: Sc[bh][q][k] = sum_d Qf[bh][q][d]*Kf[bh][k][d].
// 128x128 tile, 8x8 register tile, d ascending — bit-identical rounding.
// R9 XOR-swizzle on As AND Bs transpose-stores.
// NOTE: fused score+topk CLOSED after 4 attempts (see gemm_body header).
// ---------------------------------------------------------------------------
__global__ __launch_bounds__(256) void k_score(
    const float* __restrict__ Qf, const float* __restrict__ Kf,
    float* __restrict__ Sc) {
  __shared__ float As[32][132];   // [d][q], padded + swizzled
  __shared__ float Bs[32][132];   // [d][k], padded + swizzled (transposed K)
  const int bn = blockIdx.x * 128;
  const int bm = blockIdx.y * 128;
  const int bh = blockIdx.z;
  const float* A = Qf + (size_t)bh * (TT * 64);
  const float* K = Kf + (size_t)bh * (TT * 64);
  float* out = Sc + (size_t)bh * (TT * 1024);
  const int tid = threadIdx.x;
  const int tx = tid & 15;
  const int ty = tid >> 4;
  float acc[8][8];
#pragma unroll
  for (int i = 0; i < 8; ++i)
#pragma unroll
    for (int j = 0; j < 8; ++j) acc[i][j] = 0.f;
  for (int k0 = 0; k0 < 64; k0 += 32) {
#pragma unroll
    for (int i = 0; i < 4; ++i) {
      int idx = i * 256 + tid;
      int row = idx >> 3;           // 0..127
      int c4 = (idx & 7) << 2;
      int sw = (idx & 7) << 3;      // swizzle bits 3-5
      int rs = row ^ sw;            // 0..127
      float4 av = *(const float4*)&A[(size_t)(bm + row) * 64 + k0 + c4];
      As[c4 + 0][rs] = av.x;
      As[c4 + 1][rs] = av.y;
      As[c4 + 2][rs] = av.z;
      As[c4 + 3][rs] = av.w;
      float4 kv = *(const float4*)&K[(size_t)(bn + row) * 64 + k0 + c4];
      Bs[c4 + 0][rs] = kv.x;
      Bs[c4 + 1][rs] = kv.y;
      Bs[c4 + 2][rs] = kv.z;
      Bs[c4 + 3][rs] = kv.w;
    }
    __syncthreads();
#pragma unroll
    for (int kk = 0; kk < 32; ++kk) {
      const int sr = ((kk >> 2) & 7) << 3;
      const int abase = (ty * 8) ^ sr;
      const int bbase = (tx * 8) ^ sr;
      float4 alo = *(const float4*)&As[kk][abase];
      float4 ahi = *(const float4*)&As[kk][abase + 4];
      float4 blo = *(const float4*)&Bs[kk][bbase];
      float4 bhi = *(const float4*)&Bs[kk][bbase + 4];
      float a[8] = {alo.x, alo.y, alo.z, alo.w, ahi.x, ahi.y, ahi.z, ahi.w};
      float b[8] = {blo.x, blo.y, blo.z, blo.w, bhi.x, bhi.y, bhi.z, bhi.w};
#pragma unroll
      for (int i = 0; i < 8; ++i)
#pragma unroll
        for (int j = 0; j < 8; ++j)
          acc[i][j] = fmaf(a[i], b[j], acc[i][j]);
    }
    __syncthreads();
  }
#pragma unroll
  for (int i = 0; i < 8; ++i) {
    float4 r0 = make_float4(acc[i][0], acc[i][1], acc[i][2], acc[i][3]);
    float4 r1 = make_float4(acc[i][4], acc[i][5], acc[i][6], acc[i][7]);
    size_t base = (size_t)(bm + ty * 8 + i) * 1024 + bn + tx * 8;
    *(float4*)&out[base] = r0;
    *(float4*)&out[base + 4] = r1;
  }
}

// ---------------------------------------------------------------------------
// Top-16 + fp32 logits/softmax/attend (R1-verified v2 selection).
// ---------------------------------------------------------------------------
__global__ __launch_bounds__(256) void k_topk(
    const float* __restrict__ Sc, const float* __restrict__ Vg,
    const double4* __restrict__ sqd4, const double4* __restrict__ skd4,
    const double* __restrict__ ccd, const float* __restrict__ btaP,
    const float* __restrict__ btbP, float* __restrict__ C) {
  const int tid = threadIdx.x;
  const int lane = tid & 63;
  const int wv = tid >> 6;
  const int qg = blockIdx.x * 4 + wv;
  const int bh = qg >> 10;
  const int qa = qg & 1023;
  const int bb = bh >> 3;
  const int hh = bh & 7;
  const float* rowp = Sc + (size_t)qg * 1024;
  const float* Vbh = Vg + (size_t)bh * (TT * 64);
  float v[16];
#pragma unroll
  for (int g = 0; g < 4; ++g) {
    float4 t = *(const float4*)&rowp[g * 256 + lane * 4];
    v[g * 4 + 0] = t.x;
    v[g * 4 + 1] = t.y;
    v[g * 4 + 2] = t.z;
    v[g * 4 + 3] = t.w;
  }
  float gv[4];
  int gi[4];
  const int lbase = lane << 2;
#pragma unroll
  for (int g = 0; g < 4; ++g) {
    float nv = v[4 * g];
    int ne = 0;
#pragma unroll
    for (int e = 1; e < 4; ++e) {
      if (v[4 * g + e] > nv) { nv = v[4 * g + e]; ne = e; }
    }
    gv[g] = nv;
    gi[g] = (g << 8) | lbase | ne;
  }
  int myk = 0;
#pragma unroll 1
  for (int it = 0; it < NTOPK; ++it) {
    float cv = gv[0];
    int ci = gi[0];
#pragma unroll
    for (int g = 1; g < 4; ++g) {
      if (gv[g] > cv) { cv = gv[g]; ci = gi[g]; }
    }
    float M = cv;
#pragma unroll
    for (int off = 32; off >= 1; off >>= 1)
      M = fmaxf(M, __shfl_xor(M, off, 64));
    unsigned long long tied = __ballot(cv == M);
    int J;
    if (__popcll(tied) == 1) {
      int src = __ffsll(tied) - 1;
      J = __builtin_amdgcn_readfirstlane(__shfl(ci, src, 64));
    } else {
      int cj = (cv == M) ? ci : 0x7FFFFFFF;
#pragma unroll
      for (int off = 32; off >= 1; off >>= 1) {
        int oj = __shfl_xor(cj, off, 64);
        cj = (oj < cj) ? oj : cj;
      }
      J = __builtin_amdgcn_readfirstlane(cj);
    }
    if (lane == it) myk = J;
    const int owner = (J >> 2) & 63;
    const int g2 = J >> 8;
    const int e2 = J & 3;
    const bool isown = (lane == owner);
#pragma unroll
    for (int g = 0; g < 4; ++g) {
      if (g == g2) {
#pragma unroll
        for (int e = 0; e < 4; ++e) {
          if (e == e2) v[4 * g + e] = isown ? -INFINITY : v[4 * g + e];
        }
        float nv = v[4 * g];
        int ne = 0;
#pragma unroll
        for (int e = 1; e < 4; ++e) {
          if (v[4 * g + e] > nv) { nv = v[4 * g + e]; ne = e; }
        }
        gv[g] = nv;
        gi[g] = (g << 8) | lbase | ne;
      }
    }
  }
  const double cphi = ccd[0];
  const double ctau = ccd[1];
  const double bta0 = (double)btaP[0];
  const double btb0 = (double)btbP[0];
  double4 sq = sqd4[qg];
  float logit = -INFINITY;
  if (lane < 16) {
    double4 sk = skd4[bh * TT + myk];
    float xs = (float)(sq.x + sk.x + cphi);
    float ta = (float)(sq.y + sk.y + bta0);
    float tb = (float)(sq.z + sk.z + btb0);
    float tl = (float)(sq.w + sk.w + ctau);
    float phi = 1.f / (1.f + __expf(-xs));
    float ti = 1.f / (1.f + __expf(-(ta + tb)));
    float tau = fmaxf(tl, 0.f) + log1pf(__expf(-fabsf(tl))) + 1e-6f;
    logit = phi / tau * (1.f - __expf(-tau * ti));
  }
  float m = logit;
#pragma unroll
  for (int off = 8; off >= 1; off >>= 1) m = fmaxf(m, __shfl_xor(m, off, 64));
  float e = (lane < 16) ? __expf(logit - m) : 0.f;
  float ssum = e;
#pragma unroll
  for (int off = 8; off >= 1; off >>= 1) ssum += __shfl_xor(ssum, off, 64);
  float w = e / ssum;
  float outv = 0.f;
#pragma unroll
  for (int k2 = 0; k2 < NTOPK; ++k2) {
    float wk = __shfl(w, k2, 64);
    int ik = __shfl(myk, k2, 64);
    outv = fmaf(wk, Vbh[(size_t)ik * 64 + lane], outv);
  }
  C[(bb * TT + qa) * 512 + hh * 64 + lane] = outv;
}

// ---------------------------------------------------------------------------
// Fused fallback for small workspaces (R5-verified correct; slower).
// ---------------------------------------------------------------------------
__global__ __launch_bounds__(256) void k_attn_f(
    const float* __restrict__ Qg, const float* __restrict__ Kg,
    const float* __restrict__ Vg, const double4* __restrict__ sqd4,
    const double4* __restrict__ skd4, const double* __restrict__ ccd,
    const float* __restrict__ btaP, const float* __restrict__ btbP,
    float* __restrict__ C) {
  __shared__ float qs[8][64];
  __shared__ float sc[8][1024];
  const int bh = blockIdx.y;
  const int q0 = blockIdx.x * 8;
  const int tid = threadIdx.x;
  const int lane = tid & 63;
  const int wv = tid >> 6;
  if (tid < 128) {
    int q = tid >> 4, d4 = (tid & 15) << 2;
    *(float4*)&qs[q][d4] = *(const float4*)&Qg[(size_t)(bh * TT + q0 + q) * 64 + d4];
  }
  __syncthreads();
#pragma unroll 1
  for (int c = 0; c < 4; ++c) {
    const int kb = (c * 4 + wv) * 64;
    const float* krow = &Kg[(size_t)(bh * TT + kb + lane) * 64];
    float4 kr[16];
#pragma unroll
    for (int i = 0; i < 16; ++i) kr[i] = *(const float4*)&krow[i * 4];
#pragma unroll
    for (int q = 0; q < 8; ++q) {
      float s = 0.f;
#pragma unroll
      for (int i = 0; i < 16; ++i) {
        float4 q4 = *(const float4*)&qs[q][i * 4];
        s = fmaf(q4.x, kr[i].x, s);
        s = fmaf(q4.y, kr[i].y, s);
        s = fmaf(q4.z, kr[i].z, s);
        s = fmaf(q4.w, kr[i].w, s);
      }
      sc[q][kb + lane] = s;
    }
  }
  __syncthreads();
  const double cphi = ccd[0];
  const double ctau = ccd[1];
  const double bta0 = (double)btaP[0];
  const double btb0 = (double)btbP[0];
  const int bb = bh >> 3;
  const int hh = bh & 7;
  const float* Vbh = Vg + (size_t)bh * (TT * 64);
#pragma unroll 1
  for (int qq = 0; qq < 2; ++qq) {
    const int ql = wv * 2 + qq;
    const int qa = q0 + ql;
    float v[16];
#pragma unroll
    for (int jj = 0; jj < 16; ++jj) v[jj] = sc[ql][jj * 64 + lane];
    float gv[4];
    int gi[4];
#pragma unroll
    for (int g = 0; g < 4; ++g) {
      float nv = v[4 * g];
      int ne = 0;
#pragma unroll
      for (int e = 1; e < 4; ++e) {
        if (v[4 * g + e] > nv) { nv = v[4 * g + e]; ne = e; }
      }
      gv[g] = nv;
      gi[g] = ((4 * g + ne) << 6) | lane;
    }
    int myk = 0;
#pragma unroll 1
    for (int it = 0; it < NTOPK; ++it) {
      float cv = gv[0];
      int ci = gi[0];
#pragma unroll
      for (int g = 1; g < 4; ++g) {
        if (gv[g] > cv) { cv = gv[g]; ci = gi[g]; }
      }
      float M = cv;
#pragma unroll
      for (int off = 32; off >= 1; off >>= 1)
        M = fmaxf(M, __shfl_xor(M, off, 64));
      unsigned long long tied = __ballot(cv == M);
      int J;
      if (__popcll(tied) == 1) {
        int src = __ffsll(tied) - 1;
        J = __builtin_amdgcn_readfirstlane(__shfl(ci, src, 64));
      } else {
        int cj = (cv == M) ? ci : 0x7FFFFFFF;
#pragma unroll
        for (int off = 32; off >= 1; off >>= 1) {
          int oj = __shfl_xor(cj, off, 64);
          cj = (oj < cj) ? oj : cj;
        }
        J = __builtin_amdgcn_readfirstlane(cj);
      }
      if (lane == it) myk = J;
      const int owner = J & 63;
      const int slot2 = J >> 6;
      const int g2 = slot2 >> 2;
      const int e2 = slot2 & 3;
      const bool isown = (lane == owner);
#pragma unroll
      for (int g = 0; g < 4; ++g) {
        if (g == g2) {
#pragma unroll
          for (int e = 0; e < 4; ++e) {
            if (e == e2) v[4 * g + e] = isown ? -INFINITY : v[4 * g + e];
          }
          float nv = v[4 * g];
          int ne = 0;
#pragma unroll
          for (int e = 1; e < 4; ++e) {
            if (v[4 * g + e] > nv) { nv = v[4 * g + e]; ne = e; }
          }
          gv[g] = nv;
          gi[g] = ((4 * g + ne) << 6) | lane;
        }
      }
    }
    double4 sq = sqd4[(size_t)bh * TT + qa];
    float logit = -INFINITY;
    if (lane < 16) {
      double4 sk = skd4[bh * TT + myk];
      float xs = (float)(sq.x + sk.x + cphi);
      float ta = (float)(sq.y + sk.y + bta0);
      float tb = (float)(sq.z + sk.z + btb0);
      float tl = (float)(sq.w + sk.w + ctau);
      float phi = 1.f / (1.f + __expf(-xs));
      float ti = 1.f / (1.f + __expf(-(ta + tb)));
      float tau = fmaxf(tl, 0.f) + log1pf(__expf(-fabsf(tl))) + 1e-6f;
      logit = phi / tau * (1.f - __expf(-tau * ti));
    }
    float m = logit;
#pragma unroll
    for (int off = 8; off >= 1; off >>= 1) m = fmaxf(m, __shfl_xor(m, off, 64));
    float e = (lane < 16) ? __expf(logit - m) : 0.f;
    float ssum = e;
#pragma unroll
    for (int off = 8; off >= 1; off >>= 1) ssum += __shfl_xor(ssum, off, 64);
    float w = e / ssum;
    float outv = 0.f;
#pragma unroll
    for (int k2 = 0; k2 < NTOPK; ++k2) {
      float wk = __shfl(w, k2, 64);
      int ik = __shfl(myk, k2, 64);
      outv = fmaf(wk, Vbh[(size_t)ik * 64 + lane], outv);
    }
    C[(bb * TT + qa) * 512 + hh * 64 + lane] = outv;
  }
}

// ---------------------------------------------------------------------------
extern "C" void kernel_launch(void* const* d_in, const int* in_sizes, int n_in,
                              void* d_out, int out_size, void* d_ws, size_t ws_size,
                              hipStream_t stream) {
  (void)in_sizes; (void)n_in; (void)out_size;
  const float* x   = (const float*)d_in[0];
  const float* Wq  = (const float*)d_in[1];
  const float* bq  = (const float*)d_in[2];
  const float* Wk  = (const float*)d_in[3];
  const float* bk  = (const float*)d_in[4];
  const float* Wv  = (const float*)d_in[5];
  const float* bv  = (const float*)d_in[6];
  const float* Wo  = (const float*)d_in[7];
  const float* bo  = (const float*)d_in[8];
  const float* Wpi = (const float*)d_in[9];
  const float* bpi = (const float*)d_in[10];
  const float* Wpo = (const float*)d_in[11];
  const float* bpo = (const float*)d_in[12];
  const float* Wta = (const float*)d_in[13];
  const float* bta = (const float*)d_in[14];
  const float* Wtb = (const float*)d_in[15];
  const float* btb = (const float*)d_in[16];
  const float* Wti = (const float*)d_in[17];
  const float* bti = (const float*)d_in[18];
  const float* Wto = (const float*)d_in[19];
  const float* bto = (const float*)d_in[20];

  double* wsd = (double*)d_ws;
  double4* sqd4 = (double4*)wsd;             // 65536 doubles
  double4* skd4 = (double4*)(wsd + 65536);   // 65536 doubles
  double* wphid = wsd + 131072;              // 128
  double* wtaud = wsd + 131200;              // 128
  double* ccd   = wsd + 131328;              // 2 (pad to 131332)
  float* fs = (float*)(wsd + 131332);
  float* Qf = fs;                  // 1,048,576 floats
  float* Kf = fs + 1048576;
  float* Vf = fs + 2097152;
  float* Cf = fs + 3145728;
  float* Sc = fs + 4194304;        // 16,777,216 floats (scores, 64 MB)
  const size_t need = (size_t)131332 * 8 + (size_t)(4194304 + 16777216) * 4;

  hipLaunchKernelGGL(k_collapse64, dim3(17), dim3(256), 0, stream,
                     Wpi, bpi, Wpo, bpo, Wti, bti, Wto, bto, wphid, wtaud, ccd);
  hipLaunchKernelGGL(k_gemm_qkv, dim3(24, 32), dim3(256), 0, stream,
                     x, Wq, bq, Wk, bk, Wv, bv, Qf, Kf, Vf);
  hipLaunchKernelGGL(k_tokscal64, dim3(NTOK / 128), dim3(256), 0, stream,
                     Qf, Kf, wphid, Wta, Wtb, wtaud, sqd4, skd4);
  if (ws_size >= need) {
    hipLaunchKernelGGL(k_score, dim3(8, 8, 16), dim3(256), 0, stream, Qf, Kf, Sc);
    hipLaunchKernelGGL(k_topk, dim3(NTOK / 4), dim3(256), 0, stream,
                       Sc, Vf, sqd4, skd4, ccd, bta, btb, Cf);
  } else {
    hipLaunchKernelGGL(k_attn_f, dim3(TT / 8, NBH), dim3(256), 0, stream,
                       Qf, Kf, Vf, sqd4, skd4, ccd, bta, btb, Cf);
  }
  hipLaunchKernelGGL(k_gemm, dim3(8, 32), dim3(256), 0, stream,
                     Cf, Wo, bo, (float*)d_out, 0);
}

// Round 13
// 243.330 us; speedup vs baseline: 1.1690x; 1.0540x over previous
//
#include <hip/hip_runtime.h>
#include <math.h>

#define BDIM 2
#define TT 1024
#define NH 8
#define HD 64
#define NTOPK 16
#define NBH 16     // BDIM*NH
#define NTOK 16384 // NBH*TT

// ---------------------------------------------------------------------------
// Collapse the linear-linear pair MLPs into 128-dim fp64 vectors.
// ---------------------------------------------------------------------------
__global__ __launch_bounds__(256) void k_collapse64(
    const float* __restrict__ Wpi, const float* __restrict__ bpi,
    const float* __restrict__ Wpo, const float* __restrict__ bpo,
    const float* __restrict__ Wti, const float* __restrict__ bti,
    const float* __restrict__ Wto, const float* __restrict__ bto,
    double* __restrict__ wphid, double* __restrict__ wtaud,
    double* __restrict__ ccd) {
  int tid = threadIdx.x;
  int blk = blockIdx.x;
  if (blk < 16) {
    int r = blk * 16 + (tid >> 4);
    int l = tid & 15;
    double s = 0.;
    if (r < 128) {
      for (int i = 0; i < 32; ++i)
        s += (double)Wpi[r * 512 + l + 16 * i] * (double)Wpo[l + 16 * i];
    } else {
      int rr = r - 128;
      for (int i = 0; i < 16; ++i)
        s += (double)Wti[rr * 256 + l + 16 * i] * (double)Wto[l + 16 * i];
    }
#pragma unroll
    for (int off = 8; off >= 1; off >>= 1) s += __shfl_xor(s, off, 64);
    if (l == 0) {
      if (r < 128) wphid[r] = s;
      else wtaud[r - 128] = s;
    }
  } else {
    int lane = tid & 63;
    if (tid < 64) {
      double p = 0.;
      for (int c = lane; c < 512; c += 64) p += (double)bpi[c] * (double)Wpo[c];
#pragma unroll
      for (int off = 32; off >= 1; off >>= 1) p += __shfl_xor(p, off, 64);
      if (lane == 0) ccd[0] = p + (double)bpo[0];
    } else if (tid < 128) {
      double p = 0.;
      for (int c = lane; c < 256; c += 64) p += (double)bti[c] * (double)Wto[c];
#pragma unroll
      for (int off = 32; off >= 1; off >>= 1) p += __shfl_xor(p, off, 64);
      if (lane == 0) ccd[1] = p + (double)bto[0];
    }
  }
}

// ---------------------------------------------------------------------------
// fp32 GEMM, strict sequential-k fp32 FMA per output element (BLAS-order).
// R9 FINAL FORM: R1 structure + As XOR-swizzle (2.36M->786K conflicts,
// 54->50.3us). The residual 786K is the BENIGN 2-way A-store aliasing floor
// (64 lanes/32 banks; counted by SQ_LDS_BANK_CONFLICT, free in throughput
// per m136). R12 "fixed" it with a Bs swizzle: conflicts unchanged 786432,
// qkv 50.3->53.4 (phantom + extra addr VALU). REVERTED.
// CLOSED ARCS: R2 wave-uniform A (3.7x regress), R3 dbuf (neutral),
// R7 BM=32 (issue/ILP-bound, not occupancy), R12 Bs swizzle (phantom).
// Micro-tile >= 4x4 is load-bearing. qkv floor here: ~50us (2.4x fp32
// issue floor, barrier-drain structural).
// FUSION ARC CLOSED (R5/R6/R10/R11): all score+topk fusions 115-284us vs
// split ~87us — uncoalesced K (R5), LDS->1 blk/CU (R6), reg spill (R10),
// staging bank conflicts + occupancy (R11). Do not reopen.
// ---------------------------------------------------------------------------
__device__ __forceinline__ void gemm_body(
    const float* __restrict__ A, const float* __restrict__ W,
    const float* __restrict__ bias, float* __restrict__ out,
    int bm, int bn, int mode) {
  __shared__ float As[32][68];
  __shared__ float Bs[32][64];
  const int tid = threadIdx.x;
  const int tx = tid & 15;
  const int ty = tid >> 4;
  float acc[4][4] = {{0.f, 0.f, 0.f, 0.f}};
  for (int k0 = 0; k0 < 512; k0 += 32) {
#pragma unroll
    for (int i = 0; i < 2; ++i) {
      int idx = i * 256 + tid;     // 0..511
      int row = idx >> 3;          // 0..63
      int c4 = (idx & 7) << 2;     // 0..28
      int sw = (idx & 7) << 3;     // swizzle bits 3-5
      int rs = row ^ sw;           // 0..63
      float4 av = *(const float4*)&A[(bm + row) * 512 + k0 + c4];
      As[c4 + 0][rs] = av.x;
      As[c4 + 1][rs] = av.y;
      As[c4 + 2][rs] = av.z;
      As[c4 + 3][rs] = av.w;
    }
#pragma unroll
    for (int i = 0; i < 2; ++i) {
      int idx = i * 256 + tid;     // 0..511
      int br = idx >> 4;           // 0..31
      int bc = (idx & 15) << 2;
      *(float4*)&Bs[br][bc] = *(const float4*)&W[(k0 + br) * 512 + bn + bc];
    }
    __syncthreads();
#pragma unroll
    for (int kk = 0; kk < 32; ++kk) {
      const int sr = ((kk >> 2) & 7) << 3;
      float4 a = *(const float4*)&As[kk][(ty * 4) ^ sr];
      float4 b = *(const float4*)&Bs[kk][tx << 2];
      acc[0][0] = fmaf(a.x, b.x, acc[0][0]);
      acc[0][1] = fmaf(a.x, b.y, acc[0][1]);
      acc[0][2] = fmaf(a.x, b.z, acc[0][2]);
      acc[0][3] = fmaf(a.x, b.w, acc[0][3]);
      acc[1][0] = fmaf(a.y, b.x, acc[1][0]);
      acc[1][1] = fmaf(a.y, b.y, acc[1][1]);
      acc[1][2] = fmaf(a.y, b.z, acc[1][2]);
      acc[1][3] = fmaf(a.y, b.w, acc[1][3]);
      acc[2][0] = fmaf(a.z, b.x, acc[2][0]);
      acc[2][1] = fmaf(a.z, b.y, acc[2][1]);
      acc[2][2] = fmaf(a.z, b.z, acc[2][2]);
      acc[2][3] = fmaf(a.z, b.w, acc[2][3]);
      acc[3][0] = fmaf(a.w, b.x, acc[3][0]);
      acc[3][1] = fmaf(a.w, b.y, acc[3][1]);
      acc[3][2] = fmaf(a.w, b.z, acc[3][2]);
      acc[3][3] = fmaf(a.w, b.w, acc[3][3]);
    }
    __syncthreads();
  }
#pragma unroll
  for (int i = 0; i < 4; ++i) {
    int row = bm + ty * 4 + i;
    float4 r;
    r.x = acc[i][0] + bias[bn + tx * 4 + 0];
    r.y = acc[i][1] + bias[bn + tx * 4 + 1];
    r.z = acc[i][2] + bias[bn + tx * 4 + 2];
    r.w = acc[i][3] + bias[bn + tx * 4 + 3];
    if (mode == 0) {
      *(float4*)&out[row * 512 + bn + tx * 4] = r;
    } else {
      int bb = row >> 10;
      int tt2 = row & 1023;
      int head = bn >> 6;
      *(float4*)&out[(((bb * NH + head) * TT + tt2) << 6) + tx * 4] = r;
    }
  }
}

__global__ __launch_bounds__(256) void k_gemm(
    const float* __restrict__ A, const float* __restrict__ W,
    const float* __restrict__ bias, float* __restrict__ out, int mode) {
  gemm_body(A, W, bias, out, blockIdx.y * 64, blockIdx.x * 64, mode);
}

__global__ __launch_bounds__(256) void k_gemm_qkv(
    const float* __restrict__ A,
    const float* __restrict__ Wq, const float* __restrict__ bq,
    const float* __restrict__ Wk, const float* __restrict__ bk,
    const float* __restrict__ Wv, const float* __restrict__ bv,
    float* __restrict__ Qf, float* __restrict__ Kf, float* __restrict__ Vf) {
  int which = blockIdx.x >> 3;
  int bn = (blockIdx.x & 7) * 64;
  const float* W = (which == 0) ? Wq : (which == 1) ? Wk : Wv;
  const float* b = (which == 0) ? bq : (which == 1) ? bk : bv;
  float* out = (which == 0) ? Qf : (which == 1) ? Kf : Vf;
  gemm_body(A, W, b, out, blockIdx.y * 64, bn, 1);
}

// ---------------------------------------------------------------------------
// Per-token scalars in fp64 — v2 (R8, coalesced LDS staging).
// ---------------------------------------------------------------------------
__global__ __launch_bounds__(256) void k_tokscal64(
    const float* __restrict__ Qg, const float* __restrict__ Kg,
    const double* __restrict__ wphid, const float* __restrict__ Wta,
    const float* __restrict__ Wtb, const double* __restrict__ wtaud,
    double4* __restrict__ sqd4, double4* __restrict__ skd4) {
  __shared__ double wp[128], wa[128], wb[128], wt[128];
  __shared__ float Qs[128][64];
  __shared__ float Ks[128][64];
  const int tid = threadIdx.x;
  if (tid < 128) {
    wp[tid] = wphid[tid];
    wa[tid] = (double)Wta[tid];
    wb[tid] = (double)Wtb[tid];
    wt[tid] = wtaud[tid];
  }
  const int tok0 = blockIdx.x * 128;
#pragma unroll
  for (int i = 0; i < 8; ++i) {
    int idx = i * 256 + tid;          // 0..2047
    int row = idx >> 4;               // 0..127
    int c4 = (idx & 15) << 2;         // 0..60
    *(float4*)&Qs[row][c4] = *(const float4*)&Qg[(size_t)(tok0 + row) * 64 + c4];
    *(float4*)&Ks[row][c4] = *(const float4*)&Kg[(size_t)(tok0 + row) * 64 + c4];
  }
  __syncthreads();
  const int r = tid >> 1;        // token row 0..127
  const int h = tid & 1;         // half: d in [h*32, h*32+32)
  const int dbase = h << 5;
  double sp = 0., sa = 0., sb = 0., st = 0.;
  double kp = 0., ka = 0., kb2 = 0., kt = 0.;
#pragma unroll
  for (int i = 0; i < 32; ++i) {
    int d = dbase + ((i + r) & 31);   // rotated -> conflict-free banks
    double q = (double)Qs[r][d];
    double k = (double)Ks[r][d];
    sp += q * wp[d];
    sa += q * wa[d];
    sb += q * wb[d];
    st += q * wt[d];
    kp += k * wp[64 + d];
    ka += k * wa[64 + d];
    kb2 += k * wb[64 + d];
    kt += k * wt[64 + d];
  }
  sp += __shfl_xor(sp, 1, 64);  sa += __shfl_xor(sa, 1, 64);
  sb += __shfl_xor(sb, 1, 64);  st += __shfl_xor(st, 1, 64);
  kp += __shfl_xor(kp, 1, 64);  ka += __shfl_xor(ka, 1, 64);
  kb2 += __shfl_xor(kb2, 1, 64); kt += __shfl_xor(kt, 1, 64);
  const int tok = tok0 + r;
  if (h == 0) sqd4[tok] = make_double4(sp, sa, sb, st);
  else        skd4[tok] = make_double4(kp, ka, kb2, kt);
}

// ---------------------------------------------------------------------------
// Score GEMM: Sc[bh][q][k] = sum_d Qf[bh][q][d]*Kf[bh][k][d].
// 128x128 tile, 8x8 register tile, d ascending — bit-identical rounding.
// R9 XOR-swizzle on As AND Bs transpose-stores.
// NOTE: fused score+topk CLOSED after 4 attempts (see gemm_body header).
// ---------------------------------------------------------------------------
__global__ __launch_bounds__(256) void k_score(
    const float* __restrict__ Qf, const float* __restrict__ Kf,
    float* __restrict__ Sc) {
  __shared__ float As[32][132];   // [d][q], padded + swizzled
  __shared__ float Bs[32][132];   // [d][k], padded + swizzled (transposed K)
  const int bn = blockIdx.x * 128;
  const int bm = blockIdx.y * 128;
  const int bh = blockIdx.z;
  const float* A = Qf + (size_t)bh * (TT * 64);
  const float* K = Kf + (size_t)bh * (TT * 64);
  float* out = Sc + (size_t)bh * (TT * 1024);
  const int tid = threadIdx.x;
  const int tx = tid & 15;
  const int ty = tid >> 4;
  float acc[8][8];
#pragma unroll
  for (int i = 0; i < 8; ++i)
#pragma unroll
    for (int j = 0; j < 8; ++j) acc[i][j] = 0.f;
  for (int k0 = 0; k0 < 64; k0 += 32) {
#pragma unroll
    for (int i = 0; i < 4; ++i) {
      int idx = i * 256 + tid;
      int row = idx >> 3;           // 0..127
      int c4 = (idx & 7) << 2;
      int sw = (idx & 7) << 3;      // swizzle bits 3-5
      int rs = row ^ sw;            // 0..127
      float4 av = *(const float4*)&A[(size_t)(bm + row) * 64 + k0 + c4];
      As[c4 + 0][rs] = av.x;
      As[c4 + 1][rs] = av.y;
      As[c4 + 2][rs] = av.z;
      As[c4 + 3][rs] = av.w;
      float4 kv = *(const float4*)&K[(size_t)(bn + row) * 64 + k0 + c4];
      Bs[c4 + 0][rs] = kv.x;
      Bs[c4 + 1][rs] = kv.y;
      Bs[c4 + 2][rs] = kv.z;
      Bs[c4 + 3][rs] = kv.w;
    }
    __syncthreads();
#pragma unroll
    for (int kk = 0; kk < 32; ++kk) {
      const int sr = ((kk >> 2) & 7) << 3;
      const int abase = (ty * 8) ^ sr;
      const int bbase = (tx * 8) ^ sr;
      float4 alo = *(const float4*)&As[kk][abase];
      float4 ahi = *(const float4*)&As[kk][abase + 4];
      float4 blo = *(const float4*)&Bs[kk][bbase];
      float4 bhi = *(const float4*)&Bs[kk][bbase + 4];
      float a[8] = {alo.x, alo.y, alo.z, alo.w, ahi.x, ahi.y, ahi.z, ahi.w};
      float b[8] = {blo.x, blo.y, blo.z, blo.w, bhi.x, bhi.y, bhi.z, bhi.w};
#pragma unroll
      for (int i = 0; i < 8; ++i)
#pragma unroll
        for (int j = 0; j < 8; ++j)
          acc[i][j] = fmaf(a[i], b[j], acc[i][j]);
    }
    __syncthreads();
  }
#pragma unroll
  for (int i = 0; i < 8; ++i) {
    float4 r0 = make_float4(acc[i][0], acc[i][1], acc[i][2], acc[i][3]);
    float4 r1 = make_float4(acc[i][4], acc[i][5], acc[i][6], acc[i][7]);
    size_t base = (size_t)(bm + ty * 8 + i) * 1024 + bn + tx * 8;
    *(float4*)&out[base] = r0;
    *(float4*)&out[base + 4] = r1;
  }
}

// ---------------------------------------------------------------------------
// Top-16 + fp32 logits/softmax/attend (R1-verified v2 selection).
// ---------------------------------------------------------------------------
__global__ __launch_bounds__(256) void k_topk(
    const float* __restrict__ Sc, const float* __restrict__ Vg,
    const double4* __restrict__ sqd4, const double4* __restrict__ skd4,
    const double* __restrict__ ccd, const float* __restrict__ btaP,
    const float* __restrict__ btbP, float* __restrict__ C) {
  const int tid = threadIdx.x;
  const int lane = tid & 63;
  const int wv = tid >> 6;
  const int qg = blockIdx.x * 4 + wv;
  const int bh = qg >> 10;
  const int qa = qg & 1023;
  const int bb = bh >> 3;
  const int hh = bh & 7;
  const float* rowp = Sc + (size_t)qg * 1024;
  const float* Vbh = Vg + (size_t)bh * (TT * 64);
  float v[16];
#pragma unroll
  for (int g = 0; g < 4; ++g) {
    float4 t = *(const float4*)&rowp[g * 256 + lane * 4];
    v[g * 4 + 0] = t.x;
    v[g * 4 + 1] = t.y;
    v[g * 4 + 2] = t.z;
    v[g * 4 + 3] = t.w;
  }
  float gv[4];
  int gi[4];
  const int lbase = lane << 2;
#pragma unroll
  for (int g = 0; g < 4; ++g) {
    float nv = v[4 * g];
    int ne = 0;
#pragma unroll
    for (int e = 1; e < 4; ++e) {
      if (v[4 * g + e] > nv) { nv = v[4 * g + e]; ne = e; }
    }
    gv[g] = nv;
    gi[g] = (g << 8) | lbase | ne;
  }
  int myk = 0;
#pragma unroll 1
  for (int it = 0; it < NTOPK; ++it) {
    float cv = gv[0];
    int ci = gi[0];
#pragma unroll
    for (int g = 1; g < 4; ++g) {
      if (gv[g] > cv) { cv = gv[g]; ci = gi[g]; }
    }
    float M = cv;
#pragma unroll
    for (int off = 32; off >= 1; off >>= 1)
      M = fmaxf(M, __shfl_xor(M, off, 64));
    unsigned long long tied = __ballot(cv == M);
    int J;
    if (__popcll(tied) == 1) {
      int src = __ffsll(tied) - 1;
      J = __builtin_amdgcn_readfirstlane(__shfl(ci, src, 64));
    } else {
      int cj = (cv == M) ? ci : 0x7FFFFFFF;
#pragma unroll
      for (int off = 32; off >= 1; off >>= 1) {
        int oj = __shfl_xor(cj, off, 64);
        cj = (oj < cj) ? oj : cj;
      }
      J = __builtin_amdgcn_readfirstlane(cj);
    }
    if (lane == it) myk = J;
    const int owner = (J >> 2) & 63;
    const int g2 = J >> 8;
    const int e2 = J & 3;
    const bool isown = (lane == owner);
#pragma unroll
    for (int g = 0; g < 4; ++g) {
      if (g == g2) {
#pragma unroll
        for (int e = 0; e < 4; ++e) {
          if (e == e2) v[4 * g + e] = isown ? -INFINITY : v[4 * g + e];
        }
        float nv = v[4 * g];
        int ne = 0;
#pragma unroll
        for (int e = 1; e < 4; ++e) {
          if (v[4 * g + e] > nv) { nv = v[4 * g + e]; ne = e; }
        }
        gv[g] = nv;
        gi[g] = (g << 8) | lbase | ne;
      }
    }
  }
  const double cphi = ccd[0];
  const double ctau = ccd[1];
  const double bta0 = (double)btaP[0];
  const double btb0 = (double)btbP[0];
  double4 sq = sqd4[qg];
  float logit = -INFINITY;
  if (lane < 16) {
    double4 sk = skd4[bh * TT + myk];
    float xs = (float)(sq.x + sk.x + cphi);
    float ta = (float)(sq.y + sk.y + bta0);
    float tb = (float)(sq.z + sk.z + btb0);
    float tl = (float)(sq.w + sk.w + ctau);
    float phi = 1.f / (1.f + __expf(-xs));
    float ti = 1.f / (1.f + __expf(-(ta + tb)));
    float tau = fmaxf(tl, 0.f) + log1pf(__expf(-fabsf(tl))) + 1e-6f;
    logit = phi / tau * (1.f - __expf(-tau * ti));
  }
  float m = logit;
#pragma unroll
  for (int off = 8; off >= 1; off >>= 1) m = fmaxf(m, __shfl_xor(m, off, 64));
  float e = (lane < 16) ? __expf(logit - m) : 0.f;
  float ssum = e;
#pragma unroll
  for (int off = 8; off >= 1; off >>= 1) ssum += __shfl_xor(ssum, off, 64);
  float w = e / ssum;
  float outv = 0.f;
#pragma unroll
  for (int k2 = 0; k2 < NTOPK; ++k2) {
    float wk = __shfl(w, k2, 64);
    int ik = __shfl(myk, k2, 64);
    outv = fmaf(wk, Vbh[(size_t)ik * 64 + lane], outv);
  }
  C[(bb * TT + qa) * 512 + hh * 64 + lane] = outv;
}

// ---------------------------------------------------------------------------
// Fused fallback for small workspaces (R5-verified correct; slower).
// ---------------------------------------------------------------------------
__global__ __launch_bounds__(256) void k_attn_f(
    const float* __restrict__ Qg, const float* __restrict__ Kg,
    const float* __restrict__ Vg, const double4* __restrict__ sqd4,
    const double4* __restrict__ skd4, const double* __restrict__ ccd,
    const float* __restrict__ btaP, const float* __restrict__ btbP,
    float* __restrict__ C) {
  __shared__ float qs[8][64];
  __shared__ float sc[8][1024];
  const int bh = blockIdx.y;
  const int q0 = blockIdx.x * 8;
  const int tid = threadIdx.x;
  const int lane = tid & 63;
  const int wv = tid >> 6;
  if (tid < 128) {
    int q = tid >> 4, d4 = (tid & 15) << 2;
    *(float4*)&qs[q][d4] = *(const float4*)&Qg[(size_t)(bh * TT + q0 + q) * 64 + d4];
  }
  __syncthreads();
#pragma unroll 1
  for (int c = 0; c < 4; ++c) {
    const int kb = (c * 4 + wv) * 64;
    const float* krow = &Kg[(size_t)(bh * TT + kb + lane) * 64];
    float4 kr[16];
#pragma unroll
    for (int i = 0; i < 16; ++i) kr[i] = *(const float4*)&krow[i * 4];
#pragma unroll
    for (int q = 0; q < 8; ++q) {
      float s = 0.f;
#pragma unroll
      for (int i = 0; i < 16; ++i) {
        float4 q4 = *(const float4*)&qs[q][i * 4];
        s = fmaf(q4.x, kr[i].x, s);
        s = fmaf(q4.y, kr[i].y, s);
        s = fmaf(q4.z, kr[i].z, s);
        s = fmaf(q4.w, kr[i].w, s);
      }
      sc[q][kb + lane] = s;
    }
  }
  __syncthreads();
  const double cphi = ccd[0];
  const double ctau = ccd[1];
  const double bta0 = (double)btaP[0];
  const double btb0 = (double)btbP[0];
  const int bb = bh >> 3;
  const int hh = bh & 7;
  const float* Vbh = Vg + (size_t)bh * (TT * 64);
#pragma unroll 1
  for (int qq = 0; qq < 2; ++qq) {
    const int ql = wv * 2 + qq;
    const int qa = q0 + ql;
    float v[16];
#pragma unroll
    for (int jj = 0; jj < 16; ++jj) v[jj] = sc[ql][jj * 64 + lane];
    float gv[4];
    int gi[4];
#pragma unroll
    for (int g = 0; g < 4; ++g) {
      float nv = v[4 * g];
      int ne = 0;
#pragma unroll
      for (int e = 1; e < 4; ++e) {
        if (v[4 * g + e] > nv) { nv = v[4 * g + e]; ne = e; }
      }
      gv[g] = nv;
      gi[g] = ((4 * g + ne) << 6) | lane;
    }
    int myk = 0;
#pragma unroll 1
    for (int it = 0; it < NTOPK; ++it) {
      float cv = gv[0];
      int ci = gi[0];
#pragma unroll
      for (int g = 1; g < 4; ++g) {
        if (gv[g] > cv) { cv = gv[g]; ci = gi[g]; }
      }
      float M = cv;
#pragma unroll
      for (int off = 32; off >= 1; off >>= 1)
        M = fmaxf(M, __shfl_xor(M, off, 64));
      unsigned long long tied = __ballot(cv == M);
      int J;
      if (__popcll(tied) == 1) {
        int src = __ffsll(tied) - 1;
        J = __builtin_amdgcn_readfirstlane(__shfl(ci, src, 64));
      } else {
        int cj = (cv == M) ? ci : 0x7FFFFFFF;
#pragma unroll
        for (int off = 32; off >= 1; off >>= 1) {
          int oj = __shfl_xor(cj, off, 64);
          cj = (oj < cj) ? oj : cj;
        }
        J = __builtin_amdgcn_readfirstlane(cj);
      }
      if (lane == it) myk = J;
      const int owner = J & 63;
      const int slot2 = J >> 6;
      const int g2 = slot2 >> 2;
      const int e2 = slot2 & 3;
      const bool isown = (lane == owner);
#pragma unroll
      for (int g = 0; g < 4; ++g) {
        if (g == g2) {
#pragma unroll
          for (int e = 0; e < 4; ++e) {
            if (e == e2) v[4 * g + e] = isown ? -INFINITY : v[4 * g + e];
          }
          float nv = v[4 * g];
          int ne = 0;
#pragma unroll
          for (int e = 1; e < 4; ++e) {
            if (v[4 * g + e] > nv) { nv = v[4 * g + e]; ne = e; }
          }
          gv[g] = nv;
          gi[g] = ((4 * g + ne) << 6) | lane;
        }
      }
    }
    double4 sq = sqd4[(size_t)bh * TT + qa];
    float logit = -INFINITY;
    if (lane < 16) {
      double4 sk = skd4[bh * TT + myk];
      float xs = (float)(sq.x + sk.x + cphi);
      float ta = (float)(sq.y + sk.y + bta0);
      float tb = (float)(sq.z + sk.z + btb0);
      float tl = (float)(sq.w + sk.w + ctau);
      float phi = 1.f / (1.f + __expf(-xs));
      float ti = 1.f / (1.f + __expf(-(ta + tb)));
      float tau = fmaxf(tl, 0.f) + log1pf(__expf(-fabsf(tl))) + 1e-6f;
      logit = phi / tau * (1.f - __expf(-tau * ti));
    }
    float m = logit;
#pragma unroll
    for (int off = 8; off >= 1; off >>= 1) m = fmaxf(m, __shfl_xor(m, off, 64));
    float e = (lane < 16) ? __expf(logit - m) : 0.f;
    float ssum = e;
#pragma unroll
    for (int off = 8; off >= 1; off >>= 1) ssum += __shfl_xor(ssum, off, 64);
    float w = e / ssum;
    float outv = 0.f;
#pragma unroll
    for (int k2 = 0; k2 < NTOPK; ++k2) {
      float wk = __shfl(w, k2, 64);
      int ik = __shfl(myk, k2, 64);
      outv = fmaf(wk, Vbh[(size_t)ik * 64 + lane], outv);
    }
    C[(bb * TT + qa) * 512 + hh * 64 + lane] = outv;
  }
}

// ---------------------------------------------------------------------------
extern "C" void kernel_launch(void* const* d_in, const int* in_sizes, int n_in,
                              void* d_out, int out_size, void* d_ws, size_t ws_size,
                              hipStream_t stream) {
  (void)in_sizes; (void)n_in; (void)out_size;
  const float* x   = (const float*)d_in[0];
  const float* Wq  = (const float*)d_in[1];
  const float* bq  = (const float*)d_in[2];
  const float* Wk  = (const float*)d_in[3];
  const float* bk  = (const float*)d_in[4];
  const float* Wv  = (const float*)d_in[5];
  const float* bv  = (const float*)d_in[6];
  const float* Wo  = (const float*)d_in[7];
  const float* bo  = (const float*)d_in[8];
  const float* Wpi = (const float*)d_in[9];
  const float* bpi = (const float*)d_in[10];
  const float* Wpo = (const float*)d_in[11];
  const float* bpo = (const float*)d_in[12];
  const float* Wta = (const float*)d_in[13];
  const float* bta = (const float*)d_in[14];
  const float* Wtb = (const float*)d_in[15];
  const float* btb = (const float*)d_in[16];
  const float* Wti = (const float*)d_in[17];
  const float* bti = (const float*)d_in[18];
  const float* Wto = (const float*)d_in[19];
  const float* bto = (const float*)d_in[20];

  double* wsd = (double*)d_ws;
  double4* sqd4 = (double4*)wsd;             // 65536 doubles
  double4* skd4 = (double4*)(wsd + 65536);   // 65536 doubles
  double* wphid = wsd + 131072;              // 128
  double* wtaud = wsd + 131200;              // 128
  double* ccd   = wsd + 131328;              // 2 (pad to 131332)
  float* fs = (float*)(wsd + 131332);
  float* Qf = fs;                  // 1,048,576 floats
  float* Kf = fs + 1048576;
  float* Vf = fs + 2097152;
  float* Cf = fs + 3145728;
  float* Sc = fs + 4194304;        // 16,777,216 floats (scores, 64 MB)
  const size_t need = (size_t)131332 * 8 + (size_t)(4194304 + 16777216) * 4;

  hipLaunchKernelGGL(k_collapse64, dim3(17), dim3(256), 0, stream,
                     Wpi, bpi, Wpo, bpo, Wti, bti, Wto, bto, wphid, wtaud, ccd);
  hipLaunchKernelGGL(k_gemm_qkv, dim3(24, 32), dim3(256), 0, stream,
                     x, Wq, bq, Wk, bk, Wv, bv, Qf, Kf, Vf);
  hipLaunchKernelGGL(k_tokscal64, dim3(NTOK / 128), dim3(256), 0, stream,
                     Qf, Kf, wphid, Wta, Wtb, wtaud, sqd4, skd4);
  if (ws_size >= need) {
    hipLaunchKernelGGL(k_score, dim3(8, 8, 16), dim3(256), 0, stream, Qf, Kf, Sc);
    hipLaunchKernelGGL(k_topk, dim3(NTOK / 4), dim3(256), 0, stream,
                       Sc, Vf, sqd4, skd4, ccd, bta, btb, Cf);
  } else {
    hipLaunchKernelGGL(k_attn_f, dim3(TT / 8, NBH), dim3(256), 0, stream,
                       Qf, Kf, Vf, sqd4, skd4, ccd, bta, btb, Cf);
  }
  hipLaunchKernelGGL(k_gemm, dim3(8, 32), dim3(256), 0, stream,
                     Cf, Wo, bo, (float*)d_out, 0);
}